// Round 2
// baseline (1206.331 us; speedup 1.0000x reference)
//
#include <hip/hip_runtime.h>
#include <hip/hip_bf16.h>

#define NN 100000
#define NE 1000000

// d_out layout in FLOAT32 elements, concatenated reference-return order
#define OUT_EA  6400000ull    // edge_attr echo
#define OUT_U   70400000ull   // u echo
#define OUT_EI  70401024ull   // edge_index echo (ints as floats)

// ---------------------------------------------------------------------------
// proj: k = x@Wk^T+bk, q = x@Wq^T+bq, v = x@Wv^T+bv   (fp32 vector ALU)
// Block = 256 threads (4 waves); block handles 32 node rows, 8 rows/wave.
// W staged in LDS padded [d][65] -> lane-d reads hit banks (d+k)%32: conflict-free.
// ---------------------------------------------------------------------------
__global__ __launch_bounds__(256) void proj_kernel(
    const float* __restrict__ x,
    const float* __restrict__ Wk, const float* __restrict__ bk,
    const float* __restrict__ Wq, const float* __restrict__ bq,
    const float* __restrict__ Wv, const float* __restrict__ bv,
    float* __restrict__ ko, float* __restrict__ qo, float* __restrict__ vo)
{
    __shared__ float W[3][64 * 65];
    __shared__ float bias[3][64];
    __shared__ float atile[32 * 64];
    const int tid = threadIdx.x;

    for (int i = tid; i < 64 * 64; i += 256) {
        int d = i >> 6, k = i & 63;
        W[0][d * 65 + k] = Wk[i];
        W[1][d * 65 + k] = Wq[i];
        W[2][d * 65 + k] = Wv[i];
    }
    if (tid < 64) { bias[0][tid] = bk[tid]; bias[1][tid] = bq[tid]; bias[2][tid] = bv[tid]; }

    const int lane = tid & 63;
    const int wave = tid >> 6;
    const int base = blockIdx.x * 32;
    int nrows = NN - base; if (nrows > 32) nrows = 32;
    __syncthreads();

    for (int i = tid; i < nrows * 16; i += 256)
        ((float4*)atile)[i] = ((const float4*)(x + (size_t)base * 64))[i];
    __syncthreads();

    const int m0 = wave * 8;
    float ak[8], aq[8], av8[8];
#pragma unroll
    for (int m = 0; m < 8; m++) { ak[m] = bias[0][lane]; aq[m] = bias[1][lane]; av8[m] = bias[2][lane]; }

    const float* wk = &W[0][lane * 65];
    const float* wq = &W[1][lane * 65];
    const float* wv = &W[2][lane * 65];

    for (int k4 = 0; k4 < 64; k4 += 4) {
        float4 a4[8];
#pragma unroll
        for (int m = 0; m < 8; m++) a4[m] = *(const float4*)&atile[(m0 + m) * 64 + k4];
#pragma unroll
        for (int j = 0; j < 4; j++) {
            float wkj = wk[k4 + j], wqj = wq[k4 + j], wvj = wv[k4 + j];
#pragma unroll
            for (int m = 0; m < 8; m++) {
                float a = (j == 0) ? a4[m].x : (j == 1) ? a4[m].y : (j == 2) ? a4[m].z : a4[m].w;
                ak[m]  = fmaf(wkj, a, ak[m]);
                aq[m]  = fmaf(wqj, a, aq[m]);
                av8[m] = fmaf(wvj, a, av8[m]);
            }
        }
    }
#pragma unroll
    for (int m = 0; m < 8; m++) {
        int row = base + m0 + m;
        if (row < NN) {
            ko[(size_t)row * 64 + lane] = ak[m];
            qo[(size_t)row * 64 + lane] = aq[m];
            vo[(size_t)row * 64 + lane] = av8[m];
        }
    }
}

// ---------------------------------------------------------------------------
// edge: e = edge_attr@We^T+be (fused, never materialized), gather k/q/v,
// gated message, atomic scatter into agg. Also writes float32 edge_attr echo
// during staging (ea read once, serves GEMM + echo).
// ---------------------------------------------------------------------------
__global__ __launch_bounds__(256) void edge_kernel(
    const float* __restrict__ ea, const int* __restrict__ ei,
    const float* __restrict__ We, const float* __restrict__ be,
    const float* __restrict__ ko, const float* __restrict__ qo, const float* __restrict__ vo,
    float* __restrict__ agg, float* __restrict__ out)
{
    __shared__ float W[64 * 65];
    __shared__ float bias[64];
    __shared__ float atile[32 * 64];
    const int tid = threadIdx.x;

    for (int i = tid; i < 64 * 64; i += 256) {
        int d = i >> 6, k = i & 63;
        W[d * 65 + k] = We[i];
    }
    if (tid < 64) bias[tid] = be[tid];

    const int lane = tid & 63, wave = tid >> 6, m0 = wave * 8;
    const float* wrow = &W[lane * 65];
    float* echo = out + OUT_EA;

    for (int base = blockIdx.x * 32; base < NE; base += gridDim.x * 32) {
        __syncthreads();   // protect atile from previous iteration / weight staging
        for (int i = tid; i < 32 * 16; i += 256) {
            float4 f = ((const float4*)(ea + (size_t)base * 64))[i];
            ((float4*)atile)[i] = f;
            ((float4*)(echo + (size_t)base * 64))[i] = f;
        }
        __syncthreads();

        float acc[8];
#pragma unroll
        for (int m = 0; m < 8; m++) acc[m] = bias[lane];

        for (int k4 = 0; k4 < 64; k4 += 4) {
            float4 a4[8];
#pragma unroll
            for (int m = 0; m < 8; m++) a4[m] = *(const float4*)&atile[(m0 + m) * 64 + k4];
#pragma unroll
            for (int j = 0; j < 4; j++) {
                float w = wrow[k4 + j];
#pragma unroll
                for (int m = 0; m < 8; m++) {
                    float a = (j == 0) ? a4[m].x : (j == 1) ? a4[m].y : (j == 2) ? a4[m].z : a4[m].w;
                    acc[m] = fmaf(w, a, acc[m]);
                }
            }
        }
#pragma unroll
        for (int m = 0; m < 8; m++) {
            int e = base + m0 + m;
            int s = ei[e];
            int t = ei[NE + e];
            float ev = acc[m];
            float kd = ko[(size_t)t * 64 + lane];
            float qj = qo[(size_t)s * 64 + lane];
            float vj = vo[(size_t)s * 64 + lane];
            float z = kd + qj + ev + ev;               // (k_i+e) + (q_j+e)
            float g = 1.0f / (1.0f + __expf(-z));
            atomicAdd(&agg[(size_t)t * 64 + lane], g * (vj + ev));
        }
    }
}

// ---------------------------------------------------------------------------
// final: out = relu(agg + x@Ws^T + bs) -> float32
// ---------------------------------------------------------------------------
__global__ __launch_bounds__(256) void final_kernel(
    const float* __restrict__ x, const float* __restrict__ Ws, const float* __restrict__ bs,
    const float* __restrict__ agg, float* __restrict__ out)
{
    __shared__ float W[64 * 65];
    __shared__ float bias[64];
    __shared__ float atile[32 * 64];
    const int tid = threadIdx.x;

    for (int i = tid; i < 64 * 64; i += 256) {
        int d = i >> 6, k = i & 63;
        W[d * 65 + k] = Ws[i];
    }
    if (tid < 64) bias[tid] = bs[tid];

    const int lane = tid & 63, wave = tid >> 6, m0 = wave * 8;
    const int base = blockIdx.x * 32;
    int nrows = NN - base; if (nrows > 32) nrows = 32;
    __syncthreads();

    for (int i = tid; i < nrows * 16; i += 256)
        ((float4*)atile)[i] = ((const float4*)(x + (size_t)base * 64))[i];
    __syncthreads();

    float acc[8];
#pragma unroll
    for (int m = 0; m < 8; m++) acc[m] = bias[lane];
    const float* wrow = &W[lane * 65];

    for (int k4 = 0; k4 < 64; k4 += 4) {
        float4 a4[8];
#pragma unroll
        for (int m = 0; m < 8; m++) a4[m] = *(const float4*)&atile[(m0 + m) * 64 + k4];
#pragma unroll
        for (int j = 0; j < 4; j++) {
            float w = wrow[k4 + j];
#pragma unroll
            for (int m = 0; m < 8; m++) {
                float a = (j == 0) ? a4[m].x : (j == 1) ? a4[m].y : (j == 2) ? a4[m].z : a4[m].w;
                acc[m] = fmaf(w, a, acc[m]);
            }
        }
    }
#pragma unroll
    for (int m = 0; m < 8; m++) {
        int row = base + m0 + m;
        if (row < NN) {
            float r = acc[m] + agg[(size_t)row * 64 + lane];
            out[(size_t)row * 64 + lane] = r > 0.0f ? r : 0.0f;
        }
    }
}

// ---------------------------------------------------------------------------
// echo u (1024 floats) and edge_index (2M ints -> floats)
// ---------------------------------------------------------------------------
__global__ __launch_bounds__(256) void echo_kernel(
    const float* __restrict__ u, const int* __restrict__ ei, float* __restrict__ out)
{
    int i = blockIdx.x * 256 + threadIdx.x;
    if (i < 1024) out[OUT_U + i] = u[i];
    if (i < 2000000) out[OUT_EI + i] = (float)ei[i];
}

extern "C" void kernel_launch(void* const* d_in, const int* in_sizes, int n_in,
                              void* d_out, int out_size, void* d_ws, size_t ws_size,
                              hipStream_t stream)
{
    const float* x  = (const float*)d_in[0];
    const int*   ei = (const int*)d_in[1];
    const float* ea = (const float*)d_in[2];
    const float* u  = (const float*)d_in[3];
    // d_in[4] = batch (unused by reference output)
    const float* Wk = (const float*)d_in[5];
    const float* bk = (const float*)d_in[6];
    const float* Wq = (const float*)d_in[7];
    const float* bq = (const float*)d_in[8];
    const float* Wv = (const float*)d_in[9];
    const float* bv = (const float*)d_in[10];
    const float* We = (const float*)d_in[11];
    const float* be = (const float*)d_in[12];
    const float* Ws = (const float*)d_in[13];
    const float* bs = (const float*)d_in[14];
    float* out = (float*)d_out;

    float* ws  = (float*)d_ws;
    float* ko  = ws;
    float* qo  = ws + 6400000;
    float* vo  = ws + 12800000;
    float* agg = ws + 19200000;   // 4 x 25.6MB = 102.4MB of workspace

    hipMemsetAsync(agg, 0, (size_t)6400000 * 4, stream);
    proj_kernel <<<3125, 256, 0, stream>>>(x, Wk, bk, Wq, bq, Wv, bv, ko, qo, vo);
    edge_kernel <<<2048, 256, 0, stream>>>(ea, ei, We, be, ko, qo, vo, agg, out);
    final_kernel<<<3125, 256, 0, stream>>>(x, Ws, bs, agg, out);
    echo_kernel <<<7813, 256, 0, stream>>>(u, ei, out);
}